// Round 1
// 410.091 us; speedup vs baseline: 1.0567x; 1.0567x over previous
//
#include <hip/hip_runtime.h>
#include <cstdint>
#include <cstddef>

// out[m,n] = scale[m]*wscale[n]*(sum_k q[m,k]*w8[n,k] - azp[m]*azp_adj[n]) + bias[n]
// M=8192, K=4096, N=4096. Exact int8 path.

#define M_DIM 8192
#define K_DIM 4096
#define N_DIM 4096
#define NT (K_DIM / 64)   // 64 K-tiles of BK=64

typedef int v4i __attribute__((ext_vector_type(4)));

// ---------------------------------------------------------------------------
// Kernel 1 (fused): blocks [0, M) do per-token quant; blocks [M, M+N) do
// weight prep. Both bodies are bit-identical to the previously verified
// kernels; fusing removes one launch boundary and overlaps two independent
// memory-bound passes.
// ---------------------------------------------------------------------------
__global__ __launch_bounds__(256) void prep_kernel(
    const float* __restrict__ x, signed char* __restrict__ q,
    float* __restrict__ scale_out, int* __restrict__ azp_out,
    const int* __restrict__ w, signed char* __restrict__ w8,
    int* __restrict__ azp_adj)
{
    const int t = threadIdx.x;
    if (blockIdx.x < M_DIM) {
        // ---- per-token asymmetric quantization, one block per row ----
        const int m = blockIdx.x;
        const float4* row4 = (const float4*)(x + (size_t)m * K_DIM);

        float4 v[4];
        float mx = -3.4e38f, mn = 3.4e38f;
#pragma unroll
        for (int i = 0; i < 4; ++i) {
            v[i] = row4[i * 256 + t];                  // coalesced
            mx = fmaxf(mx, fmaxf(fmaxf(v[i].x, v[i].y), fmaxf(v[i].z, v[i].w)));
            mn = fminf(mn, fminf(fminf(v[i].x, v[i].y), fminf(v[i].z, v[i].w)));
        }
#pragma unroll
        for (int off = 32; off; off >>= 1) {
            mx = fmaxf(mx, __shfl_down(mx, off));
            mn = fminf(mn, __shfl_down(mn, off));
        }
        __shared__ float smx[4], smn[4];
        if ((t & 63) == 0) { smx[t >> 6] = mx; smn[t >> 6] = mn; }
        __syncthreads();
        mx = fmaxf(fmaxf(smx[0], smx[1]), fmaxf(smx[2], smx[3]));
        mn = fminf(fminf(smn[0], smn[1]), fminf(smn[2], smn[3]));

        const float scale = (mx - mn) / 255.0f;
        const int azp = (int)rintf(-128.0f - mn / scale);
        if (t == 0) { scale_out[m] = scale; azp_out[m] = azp; }

        int* qrow = (int*)(q + (size_t)m * K_DIM);
        const float* vf = (const float*)v;
#pragma unroll
        for (int i = 0; i < 4; ++i) {
            int b[4];
#pragma unroll
            for (int j = 0; j < 4; ++j) {
                int qv = (int)rintf(vf[4 * i + j] / scale) + azp;
                qv = qv < -128 ? -128 : (qv > 127 ? 127 : qv);
                b[j] = qv;
            }
            qrow[i * 256 + t] =
                (b[0] & 255) | ((b[1] & 255) << 8) | ((b[2] & 255) << 16) | ((b[3] & 255) << 24);
        }
    } else {
        // ---- weight prep: int32 [N,K] -> int8 [N,K] + column sums ----
        const int n = blockIdx.x - M_DIM;
        const int4* row = (const int4*)(w + (size_t)n * K_DIM);
        int* w8row = (int*)(w8 + (size_t)n * K_DIM);
        int sum = 0;
#pragma unroll
        for (int i = 0; i < 4; ++i) {
            int4 a = row[i * 256 + t];                 // coalesced
            sum += a.x + a.y + a.z + a.w;
            w8row[i * 256 + t] =
                (a.x & 255) | ((a.y & 255) << 8) | ((a.z & 255) << 16) | ((a.w & 255) << 24);
        }
#pragma unroll
        for (int off = 32; off; off >>= 1) sum += __shfl_down(sum, off);
        __shared__ int ssum[4];
        if ((t & 63) == 0) ssum[t >> 6] = sum;
        __syncthreads();
        if (t == 0) azp_adj[n] = ssum[0] + ssum[1] + ssum[2] + ssum[3];
    }
}

// ---------------------------------------------------------------------------
// Kernel 2: int8 GEMM, 256x256 tile, BK=64, 8 waves (2M x 4N), per-wave
// 128x64 via mfma_i32_16x16x64_i8. Deep pipeline:
//   - 4-deep LDS ring (4 x (16KB A + 16KB B) = 128 KiB): tile kt in buf kt&3;
//     tile kt+3 staged into buf (kt-1)&3 which was fully read one tile ago,
//     so stages never touch a live buffer (no region tracking needed).
//   - raw s_barrier (never __syncthreads) so global_load_lds stays in flight
//     across barriers; one counted s_waitcnt vmcnt(8) per tile retires
//     exactly the next tile's 4 loads (12 = 3 tiles in flight steady-state).
//   - 2 phases/tile: ph1 = m-half0 (reads A-half0 + all B frags, B cached in
//     regs), ph2 = m-half1. 16 MFMA between barriers, setprio(1) around MFMA.
//   - XOR swizzle identical (byte-wise) to the proven 128^2 kernel:
//     LDS granule (row, c) holds global (row, c ^ ((row>>1)&3)); staging
//     pre-swizzles the GLOBAL address (LDS dst stays linear base+lane*16,
//     the mandatory global_load_lds layout); reads use the same involution,
//     which collapses to the per-lane constant quad ^ ((r16>>1)&3).
//     Measured 0 bank conflicts with this pattern.
//   - XCD-aware bijective block swizzle (512 blocks, 512 % 8 == 0).
// ---------------------------------------------------------------------------
__device__ __forceinline__ void async_copy16(const signed char* g, signed char* l) {
    __builtin_amdgcn_global_load_lds(
        (const __attribute__((address_space(1))) void*)g,
        (__attribute__((address_space(3))) void*)l, 16, 0, 0);
}

__global__ __launch_bounds__(512, 2) void gemm_kernel(
    const signed char* __restrict__ A,   // [M,K] quantized activations
    const signed char* __restrict__ B,   // [N,K] int8 weights
    const float* __restrict__ scale, const int* __restrict__ azp,
    const int* __restrict__ azp_adj, const float* __restrict__ wscale,
    const float* __restrict__ bias, float* __restrict__ out)
{
    __shared__ signed char sA[4][16384];   // 4 bufs x 256 rows x 64B
    __shared__ signed char sB[4][16384];

    const int t = threadIdx.x;
    const int lane = t & 63;
    const int wave = t >> 6;
    const int quad = lane >> 4;
    const int r16 = lane & 15;

    // XCD-aware swizzle over the 512 blocks (bijective since 512 % 8 == 0)
    int bid = blockIdx.y * gridDim.x + blockIdx.x;
    bid = (bid & 7) * 64 + (bid >> 3);
    const int bn = (bid & 15) << 8;        // 16 n-blocks
    const int bm = (bid >> 4) << 8;        // 32 m-blocks

    const int wm = (wave >> 2) << 7;       // 0 or 128
    const int wn = (wave & 3) << 6;        // 0,64,128,192

    v4i acc[8][4];
#pragma unroll
    for (int i = 0; i < 8; ++i)
#pragma unroll
        for (int j = 0; j < 4; ++j) acc[i][j] = (v4i){0, 0, 0, 0};

    // staging: thread t fills LDS granule t of a 128-row chunk (row = t>>2,
    // colL = t&3); global col = colL ^ ((row>>1)&3) = (t&3) ^ ((t>>3)&3).
    // Row-periodic mod 8; chunk bases (0,128) are 0 mod 8, so one expression
    // serves both chunks.
    const int srow = t >> 2;                               // 0..127
    const int scol = ((t & 3) ^ ((t >> 3) & 3)) << 4;      // pre-swizzled global col
    const signed char* ag0 = A + (size_t)(bm + srow) * K_DIM + scol;
    const signed char* ag1 = A + (size_t)(bm + 128 + srow) * K_DIM + scol;
    const signed char* bg0 = B + (size_t)(bn + srow) * K_DIM + scol;
    const signed char* bg1 = B + (size_t)(bn + 128 + srow) * K_DIM + scol;

#define STAGE_A(kt) do { const int _b = (kt) & 3; const int _ko = (kt) << 6; \
    async_copy16(ag0 + _ko, &sA[_b][t * 16]); \
    async_copy16(ag1 + _ko, &sA[_b][8192 + t * 16]); } while (0)
#define STAGE_B(kt) do { const int _b = (kt) & 3; const int _ko = (kt) << 6; \
    async_copy16(bg0 + _ko, &sB[_b][t * 16]); \
    async_copy16(bg1 + _ko, &sB[_b][8192 + t * 16]); } while (0)

    // prologue: fill tiles 0,1,2 (12 loads/wave in flight), wait for tile 0
    STAGE_A(0); STAGE_B(0);
    STAGE_A(1); STAGE_B(1);
    STAGE_A(2); STAGE_B(2);
    asm volatile("s_waitcnt vmcnt(8)" ::: "memory");
    __builtin_amdgcn_s_barrier();

    // read swizzle collapses to a per-lane constant: wm/wn/i*16 are all
    // 0 mod 8 in the row, so ((row>>1)&3) == ((r16>>1)&3).
    const int swz = quad ^ ((r16 >> 1) & 3);

    for (int kt = 0; kt < NT; ++kt) {
        const int b = kt & 3;
        const v4i* a4 = (const v4i*)&sA[b][0];
        const v4i* b4 = (const v4i*)&sB[b][0];

        // ---- phase 1: m-half 0; load all B frags (cached for phase 2) ----
        v4i af[4], bf[4];
#pragma unroll
        for (int i = 0; i < 4; ++i) {
            af[i] = a4[(wm + i * 16 + r16) * 4 + swz];
            bf[i] = b4[(wn + i * 16 + r16) * 4 + swz];
        }
        if (kt < NT - 3) STAGE_A(kt + 3);   // into buf (kt-1)&3: fully consumed
        asm volatile("" ::: "memory");
        __builtin_amdgcn_s_barrier();
        asm volatile("s_waitcnt lgkmcnt(0)" ::: "memory");
        __builtin_amdgcn_s_setprio(1);
#pragma unroll
        for (int i = 0; i < 4; ++i)
#pragma unroll
            for (int j = 0; j < 4; ++j)
                acc[i][j] = __builtin_amdgcn_mfma_i32_16x16x64_i8(af[i], bf[j], acc[i][j], 0, 0, 0);
        __builtin_amdgcn_s_setprio(0);
        asm volatile("" ::: "memory");
        __builtin_amdgcn_s_barrier();

        // ---- phase 2: m-half 1 (B frags reused from registers) ----
        v4i ah[4];
#pragma unroll
        for (int i = 0; i < 4; ++i)
            ah[i] = a4[(wm + 64 + i * 16 + r16) * 4 + swz];
        if (kt < NT - 3) STAGE_B(kt + 3);
        asm volatile("" ::: "memory");
        __builtin_amdgcn_s_barrier();
        asm volatile("s_waitcnt lgkmcnt(0)" ::: "memory");
        __builtin_amdgcn_s_setprio(1);
#pragma unroll
        for (int i = 0; i < 4; ++i)
#pragma unroll
            for (int j = 0; j < 4; ++j)
                acc[4 + i][j] = __builtin_amdgcn_mfma_i32_16x16x64_i8(ah[i], bf[j], acc[4 + i][j], 0, 0, 0);
        __builtin_amdgcn_s_setprio(0);

        // ---- end of tile: retire exactly the next tile's 4 loads ----
        if (kt < NT - 1) {
            if (kt < NT - 3)        asm volatile("s_waitcnt vmcnt(8)" ::: "memory");
            else if (kt == NT - 3)  asm volatile("s_waitcnt vmcnt(4)" ::: "memory");
            else                    asm volatile("s_waitcnt vmcnt(0)" ::: "memory");
            __builtin_amdgcn_s_barrier();
        }
    }

#undef STAGE_A
#undef STAGE_B

    // epilogue: out = scale[m]*wscale[n]*(acc - azp[m]*adj[n]) + bias[n]
#pragma unroll
    for (int i = 0; i < 8; ++i) {
        const int mbase = bm + wm + i * 16 + quad * 4;
        float sm[4]; int am[4];
#pragma unroll
        for (int r = 0; r < 4; ++r) { sm[r] = scale[mbase + r]; am[r] = azp[mbase + r]; }
#pragma unroll
        for (int j = 0; j < 4; ++j) {
            const int n = bn + wn + j * 16 + r16;
            const float wsn = wscale[n];
            const int adjn = azp_adj[n];
            const float bn_ = bias[n];
#pragma unroll
            for (int r = 0; r < 4; ++r) {
                const int c = acc[i][j][r] - am[r] * adjn;
                out[(size_t)(mbase + r) * N_DIM + n] = sm[r] * wsn * (float)c + bn_;
            }
        }
    }
}

// ---------------------------------------------------------------------------
extern "C" void kernel_launch(void* const* d_in, const int* in_sizes, int n_in,
                              void* d_out, int out_size, void* d_ws, size_t ws_size,
                              hipStream_t stream) {
    const float* x      = (const float*)d_in[0];
    const int*   w      = (const int*)d_in[1];
    const float* wscale = (const float*)d_in[2];
    const float* bias   = (const float*)d_in[3];
    float* out = (float*)d_out;

    char* ws = (char*)d_ws;
    signed char* q8  = (signed char*)ws;                         // 32 MiB
    signed char* w8  = (signed char*)(ws + 33554432);            // 16 MiB
    float* scl       = (float*)(ws + 50331648);                  // 32 KiB
    int*   azp       = (int*)(ws + 50331648 + 32768);            // 32 KiB
    int*   adj       = (int*)(ws + 50331648 + 65536);            // 16 KiB

    prep_kernel<<<M_DIM + N_DIM, 256, 0, stream>>>(x, q8, scl, azp, w, w8, adj);
    dim3 grid(N_DIM / 256, M_DIM / 256);
    gemm_kernel<<<grid, 512, 0, stream>>>(q8, w8, scl, azp, adj, wscale, bias, out);
}